// Round 6
// baseline (92802.338 us; speedup 1.0000x reference)
//
#include <hip/hip_runtime.h>
#include <hip/hip_fp16.h>

// LSTMTrajectoryEncoder on MI355X.
// Phase 0: compact_kernel — pos[t] = exclusive prefix of mask (masked LSTM
//   steps are exact carry no-ops and are skipped entirely).
// Phase 1: zx_kernel — R15 BYTE-EXACT (known-good producer): zx row for
//   active step t written to compacted slot pos[t], f16, pre-scaled by exp2
//   gate constants, layout [slot][(u>>5)*128 + (u&15)*8 + ((u>>4)&1)*4 + g].
// Phase 2: scan_kernel (1 block, 256 thr, 4 waves, 1 wave/SIMD):
//   R20: R17/R18/R19 failed with BIT-IDENTICAL absmax across different
//   decompositions AND different zc layouts — exonerating the zc mapping,
//   the decomposition, and the exchange pattern. The only shared unvetted
//   piece is the f16 fdot2 pipeline (R15 vindicated f16 data via MFMA, not
//   dot2). Removed entirely: z = h @ Wh via plain f32 v_fma_f32 with f32
//   pre-scaled weights (256 pinned VGPRs) and f32 h in LDS. 256 FMA/lane/
//   step = 512 SIMD-cyc core — same floor as R15's MFMA but without R15's
//   ~400 cyc readout/select overhead.
//   R21: R20 failed to COMPILE — struct float4 can't be a tied "+v" asm
//   operand ("tied indirect register inputs"). Weight fragments + h chunks
//   now ext_vector_type(4) floats (VGPR quads, as u32x4 was in R16-R19),
//   one asm pin per operand. No logic change.
//     - lane (w, gh=lane>>5, ulo=lane&31) owns unit u=32w+ulo and gates
//       {2gh, 2gh+1} over the FULL K=128 (4 lo/hi-K accum chains).
//     - zc u32 read index = w*64 + (ulo&15)*4 + (ulo>>4)*2 + gh (R15 layout).
//     - cross-lane: 2 post-nonlinearity scalars via __shfl_xor(.,32).
//     - h broadcast: 32x wave-uniform ds_read_b128 (f32), overlapped w/ FMA.
//   lgkmcnt-only barrier, 2-step unroll + 2-deep zc prefetch retained.

#define TT   65536
#define DINN 128
#define HH   128
#define G4   512     // 4*H
#define NEG  0.01f
#define ROWS 16      // t-rows per GEMM block
#define CTH  1024    // compaction threads

#define SC_SIG  (-1.4426950408889634f)   // -log2(e)
#define SC_TANH ( 2.8853900817779268f)   // +2*log2(e)

typedef unsigned int u32;
typedef float fx4 __attribute__((ext_vector_type(4)));

#if defined(__has_builtin)
#if __has_builtin(__builtin_amdgcn_rcpf)
#define RCPF(x) __builtin_amdgcn_rcpf(x)
#endif
#if __has_builtin(__builtin_amdgcn_exp2f)
#define EXP2F(x) __builtin_amdgcn_exp2f(x)
#endif
#endif
#ifndef RCPF
#define RCPF(x) (1.0f / (x))
#endif
#ifndef EXP2F
#define EXP2F(x) exp2f(x)
#endif

// LDS-only barrier: waits DS ops, leaves global loads in flight (no vmcnt drain)
#define LDS_BARRIER() asm volatile("s_waitcnt lgkmcnt(0)\n\ts_barrier" ::: "memory")

// ---------------------------------------------------------- compaction kernel
__global__ __launch_bounds__(CTH) void compact_kernel(
    const int* __restrict__ mask, int* __restrict__ pos, int* __restrict__ cnt_out)
{
    __shared__ int sc[CTH];
    const int th   = threadIdx.x;
    const int base = th * (TT / CTH);
    int cnt = 0;
    #pragma unroll 8
    for (int k = 0; k < TT / CTH; ++k) cnt += (mask[base + k] != 0);
    sc[th] = cnt;
    __syncthreads();
    for (int off = 1; off < CTH; off <<= 1) {      // inclusive Hillis-Steele
        int v = sc[th];
        int u = (th >= off) ? sc[th - off] : 0;
        __syncthreads();
        sc[th] = v + u;
        __syncthreads();
    }
    int p = sc[th] - cnt;                          // exclusive prefix
    for (int k = 0; k < TT / CTH; ++k) {
        int t = base + k;
        pos[t] = p;
        p += (mask[t] != 0);
    }
    if (th == CTH - 1) cnt_out[0] = sc[CTH - 1];
}

// ---------------------------------------------------------------- GEMM kernel
__global__ __launch_bounds__(512) void zx_kernel(
    const float* __restrict__ x, const float* __restrict__ W_in,
    const float* __restrict__ b_in, const float* __restrict__ Wi,
    const float* __restrict__ b_lstm, const int* __restrict__ mask,
    const int* __restrict__ pos, __half* __restrict__ zc)
{
    __shared__ float xt[ROWS][DINN];
    __shared__ float xp[ROWS][DINN];
    const int tid = threadIdx.x;
    const int t0  = blockIdx.x * ROWS;

    {
        const float4* src = (const float4*)(x + (size_t)t0 * DINN);
        ((float4*)&xt[0][0])[tid] = src[tid];
    }
    __syncthreads();

    {
        const int c  = tid & 127;
        const int r0 = tid >> 7;
        float a0 = b_in[c], a1 = a0, a2 = a0, a3 = a0;
        #pragma unroll
        for (int k4 = 0; k4 < DINN / 4; ++k4) {
            const float w0 = W_in[(k4*4+0)*DINN + c];
            const float w1 = W_in[(k4*4+1)*DINN + c];
            const float w2 = W_in[(k4*4+2)*DINN + c];
            const float w3 = W_in[(k4*4+3)*DINN + c];
            float4 v0 = *(const float4*)&xt[r0 +  0][k4*4];
            float4 v1 = *(const float4*)&xt[r0 +  4][k4*4];
            float4 v2 = *(const float4*)&xt[r0 +  8][k4*4];
            float4 v3 = *(const float4*)&xt[r0 + 12][k4*4];
            a0 += v0.x*w0 + v0.y*w1 + v0.z*w2 + v0.w*w3;
            a1 += v1.x*w0 + v1.y*w1 + v1.z*w2 + v1.w*w3;
            a2 += v2.x*w0 + v2.y*w1 + v2.z*w2 + v2.w*w3;
            a3 += v3.x*w0 + v3.y*w1 + v3.z*w2 + v3.w*w3;
        }
        xp[r0 +  0][c] = a0 >= 0.f ? a0 : NEG * a0;
        xp[r0 +  4][c] = a1 >= 0.f ? a1 : NEG * a1;
        xp[r0 +  8][c] = a2 >= 0.f ? a2 : NEG * a2;
        xp[r0 + 12][c] = a3 >= 0.f ? a3 : NEG * a3;
    }
    __syncthreads();

    {
        const int c2 = tid;
        float acc[ROWS];
        const float bl = b_lstm[c2];
        #pragma unroll
        for (int r = 0; r < ROWS; ++r) acc[r] = bl;
        #pragma unroll 4
        for (int k4 = 0; k4 < DINN / 4; ++k4) {
            const float w0 = Wi[(k4*4+0)*G4 + c2];
            const float w1 = Wi[(k4*4+1)*G4 + c2];
            const float w2 = Wi[(k4*4+2)*G4 + c2];
            const float w3 = Wi[(k4*4+3)*G4 + c2];
            #pragma unroll
            for (int r = 0; r < ROWS; ++r) {
                float4 a = *(const float4*)&xp[r][k4*4];
                acc[r] += a.x*w0 + a.y*w1 + a.z*w2 + a.w*w3;
            }
        }
        // c2 = gate*128 + unit; dst = w*128 + li*8 + a*4 + gate (pre-scaled)
        const int   gate = c2 >> 7;
        const int   unit = c2 & 127;
        const int   dst  = (unit >> 5) * 128 + (unit & 15) * 8
                         + ((unit >> 4) & 1) * 4 + gate;
        const float gsc  = (gate == 2) ? SC_TANH : SC_SIG;
        #pragma unroll
        for (int r = 0; r < ROWS; ++r) {
            const int t = t0 + r;
            if (mask[t])
                zc[(size_t)pos[t] * G4 + dst] = __float2half(acc[r] * gsc);
        }
    }
}

// ---------------------------------------------------------------- scan kernel
// weight regs (per lane): fa<j>/fb<j> : fx4 = 4 f32 along k (k=4j..4j+3),
//   j = 0..31 covers full K=128.
//   fa: gate 2gh   -> col = gh*256 + u,       scale gh ? SC_TANH : SC_SIG
//   fb: gate 2gh+1 -> col = gh*256 + 128 + u, scale SC_SIG
#define DF(j) fx4 fa##j; fx4 fb##j;
#define LF(j) { fx4 ta_, tb_;                                              \
    ta_[0] = Wh[((j)*4+0)*G4 + colA] * scA;                                \
    ta_[1] = Wh[((j)*4+1)*G4 + colA] * scA;                                \
    ta_[2] = Wh[((j)*4+2)*G4 + colA] * scA;                                \
    ta_[3] = Wh[((j)*4+3)*G4 + colA] * scA;                                \
    tb_[0] = Wh[((j)*4+0)*G4 + colB] * SC_SIG;                             \
    tb_[1] = Wh[((j)*4+1)*G4 + colB] * SC_SIG;                             \
    tb_[2] = Wh[((j)*4+2)*G4 + colB] * SC_SIG;                             \
    tb_[3] = Wh[((j)*4+3)*G4 + colB] * SC_SIG;                             \
    fa##j = ta_; fb##j = tb_; }
#define PF(j) asm volatile("" : "+v"(fa##j)); asm volatile("" : "+v"(fb##j));

#define FORJ32(M) M(0) M(1) M(2) M(3) M(4) M(5) M(6) M(7) \
                  M(8) M(9) M(10) M(11) M(12) M(13) M(14) M(15) \
                  M(16) M(17) M(18) M(19) M(20) M(21) M(22) M(23) \
                  M(24) M(25) M(26) M(27) M(28) M(29) M(30) M(31)

// 8 f32 FMAs on one fx4 h chunk (k=4J..4J+3): 4 into AA, 4 into BB
#define DOTJ(J, AA, BB) {                                                  \
    const fx4 hc_ = *(const fx4*)&hb_[(J)*4];                              \
    AA = fmaf(hc_[0], fa##J[0], AA); AA = fmaf(hc_[1], fa##J[1], AA);      \
    AA = fmaf(hc_[2], fa##J[2], AA); AA = fmaf(hc_[3], fa##J[3], AA);      \
    BB = fmaf(hc_[0], fb##J[0], BB); BB = fmaf(hc_[1], fb##J[1], BB);      \
    BB = fmaf(hc_[2], fb##J[2], BB); BB = fmaf(hc_[3], fb##J[3], BB); }

// one LSTM step; Z32 = u32 with this lane's 2 gates (pre-scaled f16)
#define STEP(Z32, PI, PO) {                                                \
    const __half2 zs = *(const __half2*)&(Z32);                            \
    const float* hb_ = hbuf[PI];                                           \
    float aA = __half2float(zs.x);   /* gate 2gh   seed */                 \
    float aB = __half2float(zs.y);   /* gate 2gh+1 seed */                 \
    float aAh = 0.f, aBh = 0.f;                                            \
    DOTJ(0,aA,aB)   DOTJ(1,aA,aB)   DOTJ(2,aA,aB)   DOTJ(3,aA,aB)         \
    DOTJ(4,aA,aB)   DOTJ(5,aA,aB)   DOTJ(6,aA,aB)   DOTJ(7,aA,aB)         \
    DOTJ(8,aA,aB)   DOTJ(9,aA,aB)   DOTJ(10,aA,aB)  DOTJ(11,aA,aB)        \
    DOTJ(12,aA,aB)  DOTJ(13,aA,aB)  DOTJ(14,aA,aB)  DOTJ(15,aA,aB)        \
    DOTJ(16,aAh,aBh) DOTJ(17,aAh,aBh) DOTJ(18,aAh,aBh) DOTJ(19,aAh,aBh)   \
    DOTJ(20,aAh,aBh) DOTJ(21,aAh,aBh) DOTJ(22,aAh,aBh) DOTJ(23,aAh,aBh)   \
    DOTJ(24,aAh,aBh) DOTJ(25,aAh,aBh) DOTJ(26,aAh,aBh) DOTJ(27,aAh,aBh)   \
    DOTJ(28,aAh,aBh) DOTJ(29,aAh,aBh) DOTJ(30,aAh,aBh) DOTJ(31,aAh,aBh)   \
    aA += aAh; aB += aBh;                                                  \
    const float rA = RCPF(1.f + EXP2F(aA));                                \
    const float q_ = RCPF(1.f + EXP2F(aB));                                \
    const float p_ = gh1 ? 1.f - 2.f * rA : rA;                            \
    const float x1 = __shfl_xor(p_, 32, 64);                               \
    const float x2 = __shfl_xor(q_, 32, 64);                               \
    const float i_s = gh1 ? x1 : p_;                                       \
    const float f_s = gh1 ? x2 : q_;                                       \
    const float g_t = gh1 ? p_ : x1;                                       \
    const float o_s = gh1 ? q_ : x2;                                       \
    c_st = f_s * c_st + i_s * g_t;                                         \
    const float t_c = 1.f - 2.f * RCPF(EXP2F(SC_TANH * c_st) + 1.f);       \
    h_st = o_s * t_c;                                                      \
    if (!gh1) hbuf[PO][u] = h_st;                                          \
    LDS_BARRIER();                                                         \
}

__global__ __launch_bounds__(256, 1)
__attribute__((amdgpu_waves_per_eu(1, 1)))
void scan_kernel(
    const __half* __restrict__ zc, const float* __restrict__ Wh,
    const int* __restrict__ cnt, const float* __restrict__ W_lat,
    const float* __restrict__ b_lat, float* __restrict__ out)
{
    const int n    = threadIdx.x;
    const int w    = n >> 6;           // wave: units [32w, 32w+32)
    const int lane = n & 63;
    const int ulo  = lane & 31;        // unit within wave
    const int gh   = lane >> 5;        // gate-half: 0 -> {i,f}, 1 -> {g,o}
    const bool gh1 = (gh == 1);
    const int u    = (w << 5) + ulo;   // unit 0..127
    const int colA = (gh << 8) + u;          // gate 2gh   column in Wh row
    const int colB = (gh << 8) + 128 + u;    // gate 2gh+1 column
    const float scA = gh1 ? SC_TANH : SC_SIG;

    FORJ32(DF)     // 64 fx4 weight fragments (256 regs, loop-invariant)
    FORJ32(LF)     // load + scale (f32, no conversion)
    FORJ32(PF)     // pin: kill rematerialization

    __shared__ __align__(16) float hbuf[2][HH];
    __shared__ float hfin[HH];
    ((float*)hbuf)[n] = 0.f;           // n<256 covers both buffers
    float c_st = 0.f, h_st = 0.f;
    __syncthreads();

    const int S = cnt[0];
    // lane's 2 gates in R15 zc layout: u32 index for unit u=32w+ulo, gate
    // pair gh: half-offset = w*128 + (ulo&15)*8 + (ulo>>4)*4 + 2gh
    const int zoff = (w << 6) + ((ulo & 15) << 2) + ((ulo >> 4) << 1) + gh;
    const u32* pz = (const u32*)zc + zoff;
    u32 z0 = pz[0];
    u32 z1 = pz[256];                  // 256 u32 per zc row
    pz += 512;

    int i = 0;
    for (; i + 1 < S; i += 2) {
        const u32 za = pz[0];          // 2-deep prefetch
        const u32 zb = pz[256];
        pz += 512;
        STEP(z0, 0, 1)     // step i   : read hbuf[0], write hbuf[1]
        STEP(z1, 1, 0)     // step i+1 : read hbuf[1], write hbuf[0]
        z0 = za;
        z1 = zb;
    }
    if (i < S) {           // odd tail
        STEP(z0, 0, 1)
    }

    // latent = h_f @ W_lat + b_lat  (fp32 final h for precision)
    if (!gh1) hfin[u] = h_st;
    __syncthreads();
    if (n < 16) {
        float acc = b_lat[n];
        #pragma unroll
        for (int k = 0; k < HH; ++k) acc += hfin[k] * W_lat[k * 16 + n];
        out[n] = acc;
    }
}

// ---------------------------------------------------------------- launcher
extern "C" void kernel_launch(void* const* d_in, const int* in_sizes, int n_in,
                              void* d_out, int out_size, void* d_ws, size_t ws_size,
                              hipStream_t stream) {
    const float* x      = (const float*)d_in[0];
    const int*   mask   = (const int*)  d_in[1];
    const float* W_in   = (const float*)d_in[2];
    const float* b_in   = (const float*)d_in[3];
    const float* Wi     = (const float*)d_in[4];
    const float* Wh     = (const float*)d_in[5];
    const float* b_lstm = (const float*)d_in[6];
    const float* W_lat  = (const float*)d_in[7];
    const float* b_lat  = (const float*)d_in[8];
    float* out = (float*)d_out;

    __half* zc  = (__half*)d_ws;                               // (TT+4) rows
    int*    pos = (int*)((char*)d_ws + (size_t)(TT + 4) * G4 * 2);
    int*    cnt = pos + TT;

    compact_kernel<<<1, CTH, 0, stream>>>(mask, pos, cnt);
    zx_kernel<<<TT / ROWS, 512, 0, stream>>>(x, W_in, b_in, Wi, b_lstm,
                                             mask, pos, zc);
    scan_kernel<<<1, 256, 0, stream>>>(zc, Wh, cnt, W_lat, b_lat, out);
}

// Round 7
// 36841.455 us; speedup vs baseline: 2.5190x; 2.5190x over previous
//
#include <hip/hip_runtime.h>
#include <hip/hip_fp16.h>

// LSTMTrajectoryEncoder on MI355X.
// Phase 0: compact_kernel — pos[t] = exclusive prefix of mask (masked LSTM
//   steps are exact carry no-ops and are skipped entirely).
// Phase 1: zx_kernel — R15 BYTE-EXACT (known-good producer): zx row for
//   active step t written to compacted slot pos[t], f16, pre-scaled by exp2
//   gate constants, layout [slot][(u>>5)*128 + (u&15)*8 + ((u>>4)&1)*4 + g].
// Phase 2: scan_kernel (1 block, 512 thr, 8 waves, 2 waves/SIMD):
//   R21 (passed, 121ms) proved: decomposition/zc-index/shfl are correct; the
//   R16-R19 failures trace to the fdot2 BUILTIN path; and >128 VALU-consumed
//   weight VGPRs get spilled to scratch (VGPR=152 granted vs 256 needed ->
//   ~4900 cyc/step scratch reloads). R22 fixes both:
//     - 8 waves: lane (w, g=lane>>4, ul=lane&15) owns unit u=16w+ul and ONE
//       gate g over full K=128 -> 64 u32 VGPRs of packed f16 weights (no
//       spill; ~150 total regs < 256 budget at 2 waves/EU).
//     - dot core = inline-asm v_dot2_f32_f16 (2 MAC/lane/cyc, f32 accum),
//       bypassing the suspect builtin. SIMD floor 256 cyc/step.
//     - per lane: 1 exp2 + 1 rcp (sigma & tanh share 1/(e+1)); 3 parallel
//       shfl_xor (16/32/48) gather all 4 gates; all lanes compute c,h
//       (4x redundant, consistent); g==0 lanes publish h (f16) to LDS.
//     - zc: one u16/lane/step at R15 layout index, 2-deep prefetch.
//   lgkmcnt-only barrier, 2-step unroll retained.

#define TT   65536
#define DINN 128
#define HH   128
#define G4   512     // 4*H
#define NEG  0.01f
#define ROWS 16      // t-rows per GEMM block
#define CTH  1024    // compaction threads

#define SC_SIG  (-1.4426950408889634f)   // -log2(e)
#define SC_TANH ( 2.8853900817779268f)   // +2*log2(e)

typedef unsigned int u32;
typedef unsigned short u16;
typedef u32 u32x4 __attribute__((ext_vector_type(4)));
typedef _Float16 h2v __attribute__((ext_vector_type(2)));

#if defined(__has_builtin)
#if __has_builtin(__builtin_amdgcn_rcpf)
#define RCPF(x) __builtin_amdgcn_rcpf(x)
#endif
#if __has_builtin(__builtin_amdgcn_exp2f)
#define EXP2F(x) __builtin_amdgcn_exp2f(x)
#endif
#endif
#ifndef RCPF
#define RCPF(x) (1.0f / (x))
#endif
#ifndef EXP2F
#define EXP2F(x) exp2f(x)
#endif

// LDS-only barrier: waits DS ops, leaves global loads in flight (no vmcnt drain)
#define LDS_BARRIER() asm volatile("s_waitcnt lgkmcnt(0)\n\ts_barrier" ::: "memory")

// ---------------------------------------------------------- compaction kernel
__global__ __launch_bounds__(CTH) void compact_kernel(
    const int* __restrict__ mask, int* __restrict__ pos, int* __restrict__ cnt_out)
{
    __shared__ int sc[CTH];
    const int th   = threadIdx.x;
    const int base = th * (TT / CTH);
    int cnt = 0;
    #pragma unroll 8
    for (int k = 0; k < TT / CTH; ++k) cnt += (mask[base + k] != 0);
    sc[th] = cnt;
    __syncthreads();
    for (int off = 1; off < CTH; off <<= 1) {      // inclusive Hillis-Steele
        int v = sc[th];
        int u = (th >= off) ? sc[th - off] : 0;
        __syncthreads();
        sc[th] = v + u;
        __syncthreads();
    }
    int p = sc[th] - cnt;                          // exclusive prefix
    for (int k = 0; k < TT / CTH; ++k) {
        int t = base + k;
        pos[t] = p;
        p += (mask[t] != 0);
    }
    if (th == CTH - 1) cnt_out[0] = sc[CTH - 1];
}

// ---------------------------------------------------------------- GEMM kernel
__global__ __launch_bounds__(512) void zx_kernel(
    const float* __restrict__ x, const float* __restrict__ W_in,
    const float* __restrict__ b_in, const float* __restrict__ Wi,
    const float* __restrict__ b_lstm, const int* __restrict__ mask,
    const int* __restrict__ pos, __half* __restrict__ zc)
{
    __shared__ float xt[ROWS][DINN];
    __shared__ float xp[ROWS][DINN];
    const int tid = threadIdx.x;
    const int t0  = blockIdx.x * ROWS;

    {
        const float4* src = (const float4*)(x + (size_t)t0 * DINN);
        ((float4*)&xt[0][0])[tid] = src[tid];
    }
    __syncthreads();

    {
        const int c  = tid & 127;
        const int r0 = tid >> 7;
        float a0 = b_in[c], a1 = a0, a2 = a0, a3 = a0;
        #pragma unroll
        for (int k4 = 0; k4 < DINN / 4; ++k4) {
            const float w0 = W_in[(k4*4+0)*DINN + c];
            const float w1 = W_in[(k4*4+1)*DINN + c];
            const float w2 = W_in[(k4*4+2)*DINN + c];
            const float w3 = W_in[(k4*4+3)*DINN + c];
            float4 v0 = *(const float4*)&xt[r0 +  0][k4*4];
            float4 v1 = *(const float4*)&xt[r0 +  4][k4*4];
            float4 v2 = *(const float4*)&xt[r0 +  8][k4*4];
            float4 v3 = *(const float4*)&xt[r0 + 12][k4*4];
            a0 += v0.x*w0 + v0.y*w1 + v0.z*w2 + v0.w*w3;
            a1 += v1.x*w0 + v1.y*w1 + v1.z*w2 + v1.w*w3;
            a2 += v2.x*w0 + v2.y*w1 + v2.z*w2 + v2.w*w3;
            a3 += v3.x*w0 + v3.y*w1 + v3.z*w2 + v3.w*w3;
        }
        xp[r0 +  0][c] = a0 >= 0.f ? a0 : NEG * a0;
        xp[r0 +  4][c] = a1 >= 0.f ? a1 : NEG * a1;
        xp[r0 +  8][c] = a2 >= 0.f ? a2 : NEG * a2;
        xp[r0 + 12][c] = a3 >= 0.f ? a3 : NEG * a3;
    }
    __syncthreads();

    {
        const int c2 = tid;
        float acc[ROWS];
        const float bl = b_lstm[c2];
        #pragma unroll
        for (int r = 0; r < ROWS; ++r) acc[r] = bl;
        #pragma unroll 4
        for (int k4 = 0; k4 < DINN / 4; ++k4) {
            const float w0 = Wi[(k4*4+0)*G4 + c2];
            const float w1 = Wi[(k4*4+1)*G4 + c2];
            const float w2 = Wi[(k4*4+2)*G4 + c2];
            const float w3 = Wi[(k4*4+3)*G4 + c2];
            #pragma unroll
            for (int r = 0; r < ROWS; ++r) {
                float4 a = *(const float4*)&xp[r][k4*4];
                acc[r] += a.x*w0 + a.y*w1 + a.z*w2 + a.w*w3;
            }
        }
        // c2 = gate*128 + unit; dst = w*128 + li*8 + a*4 + gate (pre-scaled)
        const int   gate = c2 >> 7;
        const int   unit = c2 & 127;
        const int   dst  = (unit >> 5) * 128 + (unit & 15) * 8
                         + ((unit >> 4) & 1) * 4 + gate;
        const float gsc  = (gate == 2) ? SC_TANH : SC_SIG;
        #pragma unroll
        for (int r = 0; r < ROWS; ++r) {
            const int t = t0 + r;
            if (mask[t])
                zc[(size_t)pos[t] * G4 + dst] = __float2half(acc[r] * gsc);
        }
    }
}

// ---------------------------------------------------------------- scan kernel
// weight regs (per lane): wf<j> : u32x4 = 4 packed half2 = 8 f16 along k
//   (k = 8j .. 8j+7), j = 0..15 covers full K=128; col = g*128 + u,
//   pre-scaled by the gate's exp2 constant.
#define DW(j) u32x4 wf##j;
#define LW(j) { u32x4 t_;                                                  \
    _Pragma("unroll")                                                      \
    for (int m_ = 0; m_ < 4; ++m_) {                                       \
        h2v p_;                                                            \
        p_[0] = (_Float16)(Wh[((j)*8 + 2*m_ + 0)*G4 + col] * scW);         \
        p_[1] = (_Float16)(Wh[((j)*8 + 2*m_ + 1)*G4 + col] * scW);         \
        t_[m_] = __builtin_bit_cast(u32, p_);                              \
    }                                                                      \
    wf##j = t_; }
#define PW(j) asm volatile("" : "+v"(wf##j));

#define FORJ16(M) M(0) M(1) M(2) M(3) M(4) M(5) M(6) M(7) \
                  M(8) M(9) M(10) M(11) M(12) M(13) M(14) M(15)

// load one 16B h fragment (wave-uniform addr -> LDS broadcast)
#define LH(j) const u32x4 hq##j = hb4_[j];

// 4 inline-asm v_dot2_f32_f16 on fragment j into accumulator chain A
#define DOTF(j, A) {                                                       \
    asm("v_dot2_f32_f16 %0, %1, %2, %0" : "+v"(A) : "v"(hq##j[0]), "v"(wf##j[0])); \
    asm("v_dot2_f32_f16 %0, %1, %2, %0" : "+v"(A) : "v"(hq##j[1]), "v"(wf##j[1])); \
    asm("v_dot2_f32_f16 %0, %1, %2, %0" : "+v"(A) : "v"(hq##j[2]), "v"(wf##j[2])); \
    asm("v_dot2_f32_f16 %0, %1, %2, %0" : "+v"(A) : "v"(hq##j[3]), "v"(wf##j[3])); }

// one LSTM step; ZV = u16 with this lane's gate value (pre-scaled f16)
#define STEP(ZV, PI, PO) {                                                 \
    const u32x4* hb4_ = (const u32x4*)hbuf[PI];                            \
    LH(0) LH(1) LH(2)  LH(3)  LH(4)  LH(5)  LH(6)  LH(7)                   \
    LH(8) LH(9) LH(10) LH(11) LH(12) LH(13) LH(14) LH(15)                  \
    float a0 = __half2float(__builtin_bit_cast(__half, (u16)(ZV)));        \
    float a1 = 0.f, a2 = 0.f, a3 = 0.f;                                    \
    DOTF(0,a0)  DOTF(1,a1)  DOTF(2,a2)  DOTF(3,a3)                         \
    DOTF(4,a0)  DOTF(5,a1)  DOTF(6,a2)  DOTF(7,a3)                         \
    DOTF(8,a0)  DOTF(9,a1)  DOTF(10,a2) DOTF(11,a3)                        \
    DOTF(12,a0) DOTF(13,a1) DOTF(14,a2) DOTF(15,a3)                        \
    const float z_ = (a0 + a1) + (a2 + a3);                                \
    const float e_ = EXP2F(z_);                                            \
    const float r_ = RCPF(1.f + e_);                                       \
    const float nl = isg2 ? 1.f - 2.f * r_ : r_;                           \
    const float x16 = __shfl_xor(nl, 16, 64);                              \
    const float x32 = __shfl_xor(nl, 32, 64);                              \
    const float x48 = __shfl_xor(nl, 48, 64);                              \
    const float i_s = b5 ? (b4 ? x48 : x32) : (b4 ? x16 : nl);             \
    const float f_s = b5 ? (b4 ? x32 : x48) : (b4 ? nl  : x16);            \
    const float g_t = b5 ? (b4 ? x16 : nl)  : (b4 ? x48 : x32);            \
    const float o_s = b5 ? (b4 ? nl  : x16) : (b4 ? x32 : x48);            \
    c_st = f_s * c_st + i_s * g_t;                                         \
    const float ec_ = EXP2F(SC_TANH * c_st);                               \
    h_st = o_s * (1.f - 2.f * RCPF(ec_ + 1.f));                            \
    if (wrh) hbuf[PO][u] = __float2half(h_st);                             \
    LDS_BARRIER();                                                         \
}

__global__ __launch_bounds__(512, 2)
__attribute__((amdgpu_waves_per_eu(2, 2)))
void scan_kernel(
    const __half* __restrict__ zc, const float* __restrict__ Wh,
    const int* __restrict__ cnt, const float* __restrict__ W_lat,
    const float* __restrict__ b_lat, float* __restrict__ out)
{
    const int n    = threadIdx.x;
    const int w    = n >> 6;           // wave 0..7: units [16w, 16w+16)
    const int lane = n & 63;
    const int ul   = lane & 15;        // unit within wave
    const int g    = lane >> 4;        // gate 0..3 (i,f,g,o)
    const bool b4  = (lane >> 4) & 1;
    const bool b5  = (lane >> 5) & 1;
    const bool isg2 = (g == 2);
    const bool wrh  = (g == 0);        // gate-0 lanes publish h
    const int u    = (w << 4) + ul;    // unit 0..127
    const int col  = (g << 7) + u;     // column in Wh row (gate*128 + unit)
    const float scW = isg2 ? SC_TANH : SC_SIG;

    FORJ16(DW)     // 16 u32x4 weight fragments (64 regs, loop-invariant)
    FORJ16(LW)     // load + scale + convert + pack
    FORJ16(PW)     // pin: kill rematerialization

    __shared__ __align__(16) __half hbuf[2][HH];
    __shared__ float hfin[HH];
    if (n < 256) ((__half*)hbuf)[n] = __float2half(0.f);  // both buffers
    float c_st = 0.f, h_st = 0.f;
    __syncthreads();

    const int S = cnt[0];
    // lane's single gate in R15 zc layout (f16 index within 512-elem row)
    const int dst = (u >> 5) * 128 + (u & 15) * 8 + ((u >> 4) & 1) * 4 + g;
    const u16* pz = (const u16*)zc + dst;
    u16 z0 = pz[0];
    u16 z1 = pz[512];                  // 512 f16 per zc row
    pz += 1024;

    int i = 0;
    for (; i + 1 < S; i += 2) {
        const u16 za = pz[0];          // 2-deep prefetch
        const u16 zb = pz[512];
        pz += 1024;
        STEP(z0, 0, 1)     // step i   : read hbuf[0], write hbuf[1]
        STEP(z1, 1, 0)     // step i+1 : read hbuf[1], write hbuf[0]
        z0 = za;
        z1 = zb;
    }
    if (i < S) {           // odd tail
        STEP(z0, 0, 1)
    }

    // latent = h_f @ W_lat + b_lat  (fp32 final h for precision)
    if (wrh) hfin[u] = h_st;
    __syncthreads();
    if (n < 16) {
        float acc = b_lat[n];
        #pragma unroll
        for (int k = 0; k < HH; ++k) acc += hfin[k] * W_lat[k * 16 + n];
        out[n] = acc;
    }
}

// ---------------------------------------------------------------- launcher
extern "C" void kernel_launch(void* const* d_in, const int* in_sizes, int n_in,
                              void* d_out, int out_size, void* d_ws, size_t ws_size,
                              hipStream_t stream) {
    const float* x      = (const float*)d_in[0];
    const int*   mask   = (const int*)  d_in[1];
    const float* W_in   = (const float*)d_in[2];
    const float* b_in   = (const float*)d_in[3];
    const float* Wi     = (const float*)d_in[4];
    const float* Wh     = (const float*)d_in[5];
    const float* b_lstm = (const float*)d_in[6];
    const float* W_lat  = (const float*)d_in[7];
    const float* b_lat  = (const float*)d_in[8];
    float* out = (float*)d_out;

    __half* zc  = (__half*)d_ws;                               // (TT+4) rows
    int*    pos = (int*)((char*)d_ws + (size_t)(TT + 4) * G4 * 2);
    int*    cnt = pos + TT;

    compact_kernel<<<1, CTH, 0, stream>>>(mask, pos, cnt);
    zx_kernel<<<TT / ROWS, 512, 0, stream>>>(x, W_in, b_in, Wi, b_lstm,
                                             mask, pos, zc);
    scan_kernel<<<1, 512, 0, stream>>>(zc, Wh, cnt, W_lat, b_lat, out);
}

// Round 8
// 32251.740 us; speedup vs baseline: 2.8774x; 1.1423x over previous
//
#include <hip/hip_runtime.h>
#include <hip/hip_fp16.h>

// LSTMTrajectoryEncoder on MI355X.
// Phase 0: compact_kernel — pos[t] = exclusive prefix of mask.
// Phase 1: zx_kernel — R15 BYTE-EXACT producer: zx row for active step t at
//   compacted slot pos[t], f16, pre-scaled by exp2 gate constants, layout
//   [slot][(u>>5)*128 + (u&15)*8 + ((u>>4)&1)*4 + g].
// Phase 2: scan_kernel (1 block, 256 thr, 4 waves, 1 wave/SIMD):
//   R23: R21/R22 post-mortem — VGPR=60 + zero extra FETCH means no scratch
//   spill (weights auto-placed in AGPRs; CSV counts arch VGPRs only). R22's
//   1490 cyc/step was the DS pipe: 128 broadcast ds_read_b128 + 24 bpermute
//   per step (8 waves x 16 reads). h-broadcast demand amortizes over the
//   outputs a lane computes per h-slice -> DS-minimal shape is R16's
//   decomposition (now fully vindicated: R19 proved zc mapping, R21/R22
//   proved shfl + asm-dot2; R16's only bugs were the fdot2 BUILTIN and
//   permlane operand aliasing):
//     - lane (w, kh=lane>>5, ulo=lane&31): unit u=32w+ulo, ALL 4 gates,
//       K-half [64kh,64kh+64). Weights 4g x 64k = 128 u32 packed f16
//       (pre-scaled), pinned; ~210 regs < 256 arch cap.
//     - per wave per step: 8 ds_read_b128 h-broadcast + 4 shfl_xor(32)
//       f32 partial combine (proven R21/R22) + 1 ds_write_b16 publish
//       = 13 DS instrs (vs R22's 19 per wave x 8 waves).
//     - dot core: 128 asm v_dot2_f32_f16 / lane = 256 SIMD-cyc at 1 w/SIMD,
//       4 independent gate chains.
//     - zc seeds: uint2 (4 gates) at R15 layout, kh0 lanes seed, 2-deep
//       global prefetch (not drained by lgkm-only barrier).
//   lgkmcnt-only barrier, 2-step unroll retained.

#define TT   65536
#define DINN 128
#define HH   128
#define G4   512     // 4*H
#define NEG  0.01f
#define ROWS 16      // t-rows per GEMM block
#define CTH  1024    // compaction threads

#define SC_SIG  (-1.4426950408889634f)   // -log2(e)
#define SC_TANH ( 2.8853900817779268f)   // +2*log2(e)

typedef unsigned int u32;
typedef unsigned short u16;
typedef u32 u32x4 __attribute__((ext_vector_type(4)));
typedef _Float16 h2v __attribute__((ext_vector_type(2)));

#if defined(__has_builtin)
#if __has_builtin(__builtin_amdgcn_rcpf)
#define RCPF(x) __builtin_amdgcn_rcpf(x)
#endif
#if __has_builtin(__builtin_amdgcn_exp2f)
#define EXP2F(x) __builtin_amdgcn_exp2f(x)
#endif
#endif
#ifndef RCPF
#define RCPF(x) (1.0f / (x))
#endif
#ifndef EXP2F
#define EXP2F(x) exp2f(x)
#endif

// LDS-only barrier: waits DS ops, leaves global loads in flight (no vmcnt drain)
#define LDS_BARRIER() asm volatile("s_waitcnt lgkmcnt(0)\n\ts_barrier" ::: "memory")

// ---------------------------------------------------------- compaction kernel
__global__ __launch_bounds__(CTH) void compact_kernel(
    const int* __restrict__ mask, int* __restrict__ pos, int* __restrict__ cnt_out)
{
    __shared__ int sc[CTH];
    const int th   = threadIdx.x;
    const int base = th * (TT / CTH);
    int cnt = 0;
    #pragma unroll 8
    for (int k = 0; k < TT / CTH; ++k) cnt += (mask[base + k] != 0);
    sc[th] = cnt;
    __syncthreads();
    for (int off = 1; off < CTH; off <<= 1) {      // inclusive Hillis-Steele
        int v = sc[th];
        int u = (th >= off) ? sc[th - off] : 0;
        __syncthreads();
        sc[th] = v + u;
        __syncthreads();
    }
    int p = sc[th] - cnt;                          // exclusive prefix
    for (int k = 0; k < TT / CTH; ++k) {
        int t = base + k;
        pos[t] = p;
        p += (mask[t] != 0);
    }
    if (th == CTH - 1) cnt_out[0] = sc[CTH - 1];
}

// ---------------------------------------------------------------- GEMM kernel
__global__ __launch_bounds__(512) void zx_kernel(
    const float* __restrict__ x, const float* __restrict__ W_in,
    const float* __restrict__ b_in, const float* __restrict__ Wi,
    const float* __restrict__ b_lstm, const int* __restrict__ mask,
    const int* __restrict__ pos, __half* __restrict__ zc)
{
    __shared__ float xt[ROWS][DINN];
    __shared__ float xp[ROWS][DINN];
    const int tid = threadIdx.x;
    const int t0  = blockIdx.x * ROWS;

    {
        const float4* src = (const float4*)(x + (size_t)t0 * DINN);
        ((float4*)&xt[0][0])[tid] = src[tid];
    }
    __syncthreads();

    {
        const int c  = tid & 127;
        const int r0 = tid >> 7;
        float a0 = b_in[c], a1 = a0, a2 = a0, a3 = a0;
        #pragma unroll
        for (int k4 = 0; k4 < DINN / 4; ++k4) {
            const float w0 = W_in[(k4*4+0)*DINN + c];
            const float w1 = W_in[(k4*4+1)*DINN + c];
            const float w2 = W_in[(k4*4+2)*DINN + c];
            const float w3 = W_in[(k4*4+3)*DINN + c];
            float4 v0 = *(const float4*)&xt[r0 +  0][k4*4];
            float4 v1 = *(const float4*)&xt[r0 +  4][k4*4];
            float4 v2 = *(const float4*)&xt[r0 +  8][k4*4];
            float4 v3 = *(const float4*)&xt[r0 + 12][k4*4];
            a0 += v0.x*w0 + v0.y*w1 + v0.z*w2 + v0.w*w3;
            a1 += v1.x*w0 + v1.y*w1 + v1.z*w2 + v1.w*w3;
            a2 += v2.x*w0 + v2.y*w1 + v2.z*w2 + v2.w*w3;
            a3 += v3.x*w0 + v3.y*w1 + v3.z*w2 + v3.w*w3;
        }
        xp[r0 +  0][c] = a0 >= 0.f ? a0 : NEG * a0;
        xp[r0 +  4][c] = a1 >= 0.f ? a1 : NEG * a1;
        xp[r0 +  8][c] = a2 >= 0.f ? a2 : NEG * a2;
        xp[r0 + 12][c] = a3 >= 0.f ? a3 : NEG * a3;
    }
    __syncthreads();

    {
        const int c2 = tid;
        float acc[ROWS];
        const float bl = b_lstm[c2];
        #pragma unroll
        for (int r = 0; r < ROWS; ++r) acc[r] = bl;
        #pragma unroll 4
        for (int k4 = 0; k4 < DINN / 4; ++k4) {
            const float w0 = Wi[(k4*4+0)*G4 + c2];
            const float w1 = Wi[(k4*4+1)*G4 + c2];
            const float w2 = Wi[(k4*4+2)*G4 + c2];
            const float w3 = Wi[(k4*4+3)*G4 + c2];
            #pragma unroll
            for (int r = 0; r < ROWS; ++r) {
                float4 a = *(const float4*)&xp[r][k4*4];
                acc[r] += a.x*w0 + a.y*w1 + a.z*w2 + a.w*w3;
            }
        }
        // c2 = gate*128 + unit; dst = w*128 + li*8 + a*4 + gate (pre-scaled)
        const int   gate = c2 >> 7;
        const int   unit = c2 & 127;
        const int   dst  = (unit >> 5) * 128 + (unit & 15) * 8
                         + ((unit >> 4) & 1) * 4 + gate;
        const float gsc  = (gate == 2) ? SC_TANH : SC_SIG;
        #pragma unroll
        for (int r = 0; r < ROWS; ++r) {
            const int t = t0 + r;
            if (mask[t])
                zc[(size_t)pos[t] * G4 + dst] = __float2half(acc[r] * gsc);
        }
    }
}

// ---------------------------------------------------------------- scan kernel
// weight regs: wg<g>_<j> : u32x4 = 4 packed half2 = 8 f16 along k
//   (k = K0 + 8j .. K0 + 8j + 7, j=0..7 covers the lane's K-half),
//   col = g*128 + u, pre-scaled by the gate's exp2 constant.
#define DWG(g,j) u32x4 wg##g##_##j;
#define LWG(g,j) { u32x4 t_;                                               \
    const float sc_ = ((g) == 2) ? SC_TANH : SC_SIG;                       \
    const int col_ = ((g) << 7) + u;                                       \
    _Pragma("unroll")                                                      \
    for (int m_ = 0; m_ < 4; ++m_) {                                       \
        h2v p_;                                                            \
        p_[0] = (_Float16)(Wh[(K0 + (j)*8 + 2*m_ + 0)*G4 + col_] * sc_);   \
        p_[1] = (_Float16)(Wh[(K0 + (j)*8 + 2*m_ + 1)*G4 + col_] * sc_);   \
        t_[m_] = __builtin_bit_cast(u32, p_);                              \
    }                                                                      \
    wg##g##_##j = t_; }
#define PWG(g,j) asm volatile("" : "+v"(wg##g##_##j));

#define FORJ(M,g)  M(g,0) M(g,1) M(g,2) M(g,3) M(g,4) M(g,5) M(g,6) M(g,7)
#define FORALLW(M) FORJ(M,0) FORJ(M,1) FORJ(M,2) FORJ(M,3)

// one u32 (2 f16) of h against all 4 gate chains — independent chains
#define DOTM(j,m) {                                                        \
    asm("v_dot2_f32_f16 %0, %1, %2, %0" : "+v"(a0) : "v"(hq##j[m]), "v"(wg0_##j[m])); \
    asm("v_dot2_f32_f16 %0, %1, %2, %0" : "+v"(a1) : "v"(hq##j[m]), "v"(wg1_##j[m])); \
    asm("v_dot2_f32_f16 %0, %1, %2, %0" : "+v"(a2) : "v"(hq##j[m]), "v"(wg2_##j[m])); \
    asm("v_dot2_f32_f16 %0, %1, %2, %0" : "+v"(a3) : "v"(hq##j[m]), "v"(wg3_##j[m])); }
#define DOTJ(j) DOTM(j,0) DOTM(j,1) DOTM(j,2) DOTM(j,3)

// own + partner (lane ^ 32): __shfl_xor — proven correct in R21/R22
#define SWADD(a) { (a) += __shfl_xor((a), 32, 64); }

// one LSTM step; ZZ = uint2 with this lane's unit's 4 gates (pre-scaled f16)
#define STEP(ZZ, PI, PO) {                                                 \
    const __half2 zl = *(const __half2*)&(ZZ).x;   /* (i,f) */             \
    const __half2 zh = *(const __half2*)&(ZZ).y;   /* (g,o) */             \
    const u32x4* hb4_ = (const u32x4*)&hbuf[PI][K0];                       \
    const u32x4 hq0 = hb4_[0];                                             \
    const u32x4 hq1 = hb4_[1];                                             \
    const u32x4 hq2 = hb4_[2];                                             \
    const u32x4 hq3 = hb4_[3];                                             \
    const u32x4 hq4 = hb4_[4];                                             \
    const u32x4 hq5 = hb4_[5];                                             \
    const u32x4 hq6 = hb4_[6];                                             \
    const u32x4 hq7 = hb4_[7];                                             \
    float a0 = kh0 ? __half2float(zl.x) : 0.f;                             \
    float a1 = kh0 ? __half2float(zl.y) : 0.f;                             \
    float a2 = kh0 ? __half2float(zh.x) : 0.f;                             \
    float a3 = kh0 ? __half2float(zh.y) : 0.f;                             \
    DOTJ(0) DOTJ(1) DOTJ(2) DOTJ(3) DOTJ(4) DOTJ(5) DOTJ(6) DOTJ(7)       \
    SWADD(a0) SWADD(a1) SWADD(a2) SWADD(a3)                                \
    const float i_s = RCPF(1.f + EXP2F(a0));                               \
    const float f_s = RCPF(1.f + EXP2F(a1));                               \
    const float g_t = 1.f - 2.f * RCPF(EXP2F(a2) + 1.f);                   \
    const float o_s = RCPF(1.f + EXP2F(a3));                               \
    c_st = f_s * c_st + i_s * g_t;                                         \
    const float t_c = 1.f - 2.f * RCPF(EXP2F(SC_TANH * c_st) + 1.f);       \
    h_st = o_s * t_c;                                                      \
    if (kh0) hbuf[PO][u] = __float2half(h_st);                             \
    LDS_BARRIER();                                                         \
}

__global__ __launch_bounds__(256, 1)
__attribute__((amdgpu_waves_per_eu(1, 1)))
void scan_kernel(
    const __half* __restrict__ zc, const float* __restrict__ Wh,
    const int* __restrict__ cnt, const float* __restrict__ W_lat,
    const float* __restrict__ b_lat, float* __restrict__ out)
{
    const int n    = threadIdx.x;
    const int w    = n >> 6;           // wave: units [32w, 32w+32)
    const int lane = n & 63;
    const int ulo  = lane & 31;        // unit within wave
    const int kh   = lane >> 5;        // k-half: 0 -> k[0,64), 1 -> k[64,128)
    const bool kh0 = (kh == 0);
    const int u    = (w << 5) + ulo;   // unit 0..127
    const int K0   = kh << 6;          // k-window base (f16 elements)

    FORALLW(DWG)    // 32 u32x4 weight fragments (128 regs, loop-invariant)
    FORALLW(LWG)    // load + scale + convert + pack
    FORALLW(PWG)    // pin

    __shared__ __align__(16) __half hbuf[2][HH];
    __shared__ float hfin[HH];
    ((__half*)hbuf)[n] = __float2half(0.f);   // n<256 covers both buffers
    float c_st = 0.f, h_st = 0.f;
    __syncthreads();

    const int S = cnt[0];
    // lane's unit's 4 gates in R15 zc layout: uint2 index
    //   = w*32 + (ulo&15)*2 + ((ulo>>4)&1); both kh halves read same (bcast)
    const uint2* prow = (const uint2*)zc + (w << 5) + ((ulo & 15) << 1)
                      + ((ulo >> 4) & 1);
    uint2 z0 = prow[0];
    uint2 z1 = prow[128];              // 128 uint2 per zc row
    prow += 256;

    int i = 0;
    for (; i + 1 < S; i += 2) {
        const uint2 za = prow[0];      // 2-deep prefetch
        const uint2 zb = prow[128];
        prow += 256;
        STEP(z0, 0, 1)     // step i   : read hbuf[0], write hbuf[1]
        STEP(z1, 1, 0)     // step i+1 : read hbuf[1], write hbuf[0]
        z0 = za;
        z1 = zb;
    }
    if (i < S) {           // odd tail
        STEP(z0, 0, 1)
    }

    // latent = h_f @ W_lat + b_lat  (fp32 final h for precision)
    if (kh0) hfin[u] = h_st;
    __syncthreads();
    if (n < 16) {
        float acc = b_lat[n];
        #pragma unroll
        for (int k = 0; k < HH; ++k) acc += hfin[k] * W_lat[k * 16 + n];
        out[n] = acc;
    }
}

// ---------------------------------------------------------------- launcher
extern "C" void kernel_launch(void* const* d_in, const int* in_sizes, int n_in,
                              void* d_out, int out_size, void* d_ws, size_t ws_size,
                              hipStream_t stream) {
    const float* x      = (const float*)d_in[0];
    const int*   mask   = (const int*)  d_in[1];
    const float* W_in   = (const float*)d_in[2];
    const float* b_in   = (const float*)d_in[3];
    const float* Wi     = (const float*)d_in[4];
    const float* Wh     = (const float*)d_in[5];
    const float* b_lstm = (const float*)d_in[6];
    const float* W_lat  = (const float*)d_in[7];
    const float* b_lat  = (const float*)d_in[8];
    float* out = (float*)d_out;

    __half* zc  = (__half*)d_ws;                               // (TT+4) rows
    int*    pos = (int*)((char*)d_ws + (size_t)(TT + 4) * G4 * 2);
    int*    cnt = pos + TT;

    compact_kernel<<<1, CTH, 0, stream>>>(mask, pos, cnt);
    zx_kernel<<<TT / ROWS, 512, 0, stream>>>(x, W_in, b_in, Wi, b_lstm,
                                             mask, pos, zc);
    scan_kernel<<<1, 256, 0, stream>>>(zc, Wh, cnt, W_lat, b_lat, out);
}